// Round 10
// baseline (267.451 us; speedup 1.0000x reference)
//
#include <hip/hip_runtime.h>
#include <hip/hip_bf16.h>

#define GROUPS 12
#define POOL   64
#define TOPK   8
#define LAYERS 24
#define RANK   64
#define HID    1024
// weight_offset: [POOL, 2, HID*RANK*LAYERS]
#define D_LR   (HID * RANK * LAYERS)      // 1572864
#define POOL_STRIDE (2L * D_LR)           // 3145728

typedef __attribute__((ext_vector_type(8))) short bf16x8;
typedef __attribute__((ext_vector_type(4))) float f32x4;

__device__ __forceinline__ unsigned bfpack2(float lo, float hi) {
    float2 t; t.x = lo; t.y = hi;
    union { __hip_bfloat162 h; unsigned u; } cv;
    cv.h = __float22bfloat162_rn(t);
    return cv.u;
}

// XOR swizzle on the K-chunk index; conflict-free for the b128 write pattern
// (col=4*lane+cc) and 2-way (free) for reads (col=base+fr, chunk=kk*4+kb)
__device__ __forceinline__ int sw_idx(int col, int chunk) {
    return chunk ^ (col & 7) ^ ((col >> 2) & 7);
}

// ---------------- Phase 1: routing (one block, 768 threads) ----------------
__global__ void routing_kernel(const float* __restrict__ q,     // [64, 768]
                               const float* __restrict__ keys,  // [12, 64, 64]
                               int* __restrict__ idx_out,       // [8]
                               float* __restrict__ w_out) {     // [8]
    __shared__ float invn[64][GROUPS];
    __shared__ float qbar[GROUPS][64];
    __shared__ float simg[GROUPS][64];
    const int t = threadIdx.x;

    {
        int b = t / GROUPS, g = t % GROUPS;
        const float* row = q + b * 768 + g * 64;
        float ss = 0.f;
        #pragma unroll 8
        for (int c = 0; c < 64; ++c) { float v = row[c]; ss = fmaf(v, v, ss); }
        invn[b][g] = 1.f / fmaxf(sqrtf(ss), 1e-8f);
    }
    __syncthreads();
    {
        int g = t >> 6, c = t & 63;
        float s = 0.f;
        for (int b = 0; b < 64; ++b) s = fmaf(q[b * 768 + g * 64 + c], invn[b][g], s);
        qbar[g][c] = s;
    }
    __syncthreads();
    {
        int g = t >> 6, p = t & 63;
        const float* krow = keys + (g * 64 + p) * 64;
        float ss = 0.f, dot = 0.f;
        #pragma unroll 8
        for (int c = 0; c < 64; ++c) {
            float v = krow[c];
            ss  = fmaf(v, v, ss);
            dot = fmaf(v, qbar[g][c], dot);
        }
        simg[g][p] = dot / fmaxf(sqrtf(ss), 1e-8f);
    }
    __syncthreads();
    if (t < 64) {
        float s = 0.f;
        for (int g = 0; g < GROUPS; ++g) s += simg[g][t];
        qbar[0][t] = s * (1.f / 768.f);
    }
    __syncthreads();
    if (t == 0) {
        float ms[POOL];
        for (int p = 0; p < POOL; ++p) ms[p] = qbar[0][p];
        float sum = 0.f;
        float vals[TOPK]; int ids[TOPK];
        for (int k = 0; k < TOPK; ++k) {
            float best = -3.4e38f; int bi = 0;
            for (int p = 0; p < POOL; ++p)
                if (ms[p] > best) { best = ms[p]; bi = p; }
            vals[k] = best; ids[k] = bi;
            ms[bi] = -3.4e38f; sum += best;
        }
        float inv = 1.f / (sum + 1e-9f);
        for (int k = 0; k < TOPK; ++k) { idx_out[k] = ids[k]; w_out[k] = vals[k] * inv; }
    }
}

// ---- Phase 2: bf16 MFMA GEMM, 256(M) x 512(N) tiles, 512 thr / 8 waves ----
// 192 blocks = 24 layers x (4 m-strips x 2 n-strips). Wider N halves A's
// issued-byte redundancy: 288 MB panels + 101 MB write vs round-6's 485 MB.
// acc = 64 f32x4 (256 VGPR) + 24 f32x4 staging -> ~380 VGPR, under the ~450
// no-spill line at 2 waves/SIMD. All round-6-proven machinery retained.
__global__ __launch_bounds__(512, 2) void lowrank_mfma_kernel(
        const float* __restrict__ wo,   // [64, 2, D_LR]
        const int*   __restrict__ idx,  // [8]
        const float* __restrict__ w,    // [8]
        float*       __restrict__ out)  // [24, 1024, 1024]
{
    __shared__ uint4 As4[256][8];   // 32 KB  [col][K-chunk of 8 bf16], swizzled
    __shared__ uint4 Bs4[512][8];   // 64 KB
    __shared__ int   s_idx[TOPK];
    __shared__ float s_w[TOPK];

    const int tid = threadIdx.x;
    const int b   = blockIdx.x;       // 0..191
    const int xcd = b & 7;            // round-robin block->XCD
    const int i   = b >> 3;           // 0..23 within XCD

    const int l   = 3 * xcd + (i >> 3);   // 3 layers per XCD (L2 gang)
    const int pos = i & 7;
    const int m0  = (pos >> 1) * 256;
    const int n0  = (pos & 1) * 512;

    if (tid < TOPK) { s_idx[tid] = idx[tid]; s_w[tid] = w[tid]; }
    __syncthreads();

    const int lane = tid & 63;
    const int wave = tid >> 6;
    const int wr = wave >> 2;      // 0..1 : 128-row band (M)
    const int wc = wave & 3;       // 0..3 : 128-col band (N)
    const int fr = lane & 15;
    const int kb = lane >> 4;

    // staging geometry: A: wave = K-row octet, lane = col-quad (256 cols)
    //                   B: wave-pair = K-row 16-group, 128 col-quads (512 cols)
    const int c4a = lane;             // A col-quad 0..63
    const int rga = wave;             // A K-octet 0..7 (= chunk)
    const int c4b = (tid & 127);      // B col-quad 0..127
    const int rgb = tid >> 7;         // B K-16-group 0..3

    f32x4 acc[8][8];
    #pragma unroll
    for (int p = 0; p < 8; ++p)
        #pragma unroll
        for (int q2 = 0; q2 < 8; ++q2) acc[p][q2] = (f32x4){0.f, 0.f, 0.f, 0.f};

    f32x4 araw[8];    // 8 K-rows x 4 cols (A)
    f32x4 braw[16];   // 16 K-rows x 4 cols (B)

    auto load_raw = [&](int s) {
        const long base = (long)s_idx[s] * POOL_STRIDE + (long)l * (RANK * HID);
        const float* pa = wo + base + (long)(rga * 8) * HID + (m0 + c4a * 4);
        const float* pb = wo + base + D_LR + (long)(rgb * 16) * HID + (n0 + c4b * 4);
        #pragma unroll
        for (int j = 0; j < 8; ++j)  araw[j] = *(const f32x4*)(pa + (long)j * HID);
        #pragma unroll
        for (int j = 0; j < 16; ++j) braw[j] = *(const f32x4*)(pb + (long)j * HID);
    };

    load_raw(0);

    for (int s = 0; s < 8; ++s) {
        const float wn = s_w[s];
        // pack A: 8 rows x 4 cols -> 1 chunk per col (w-scaled)
        #pragma unroll
        for (int cc = 0; cc < 4; ++cc) {
            const int col = c4a * 4 + cc;
            uint4 ua;
            ua.x = bfpack2(wn * araw[0][cc], wn * araw[1][cc]);
            ua.y = bfpack2(wn * araw[2][cc], wn * araw[3][cc]);
            ua.z = bfpack2(wn * araw[4][cc], wn * araw[5][cc]);
            ua.w = bfpack2(wn * araw[6][cc], wn * araw[7][cc]);
            As4[col][sw_idx(col, rga)] = ua;
        }
        // pack B: 16 rows x 4 cols -> 2 chunks per col
        #pragma unroll
        for (int cc = 0; cc < 4; ++cc) {
            const int col = c4b * 4 + cc;
            uint4 u0, u1;
            u0.x = bfpack2(braw[0][cc],  braw[1][cc]);
            u0.y = bfpack2(braw[2][cc],  braw[3][cc]);
            u0.z = bfpack2(braw[4][cc],  braw[5][cc]);
            u0.w = bfpack2(braw[6][cc],  braw[7][cc]);
            u1.x = bfpack2(braw[8][cc],  braw[9][cc]);
            u1.y = bfpack2(braw[10][cc], braw[11][cc]);
            u1.z = bfpack2(braw[12][cc], braw[13][cc]);
            u1.w = bfpack2(braw[14][cc], braw[15][cc]);
            Bs4[col][sw_idx(col, 2 * rgb)]     = u0;
            Bs4[col][sw_idx(col, 2 * rgb + 1)] = u1;
        }
        __syncthreads();

        if (s < 7) load_raw(s + 1);   // next-slot loads in flight under MFMA

        #pragma unroll
        for (int kk = 0; kk < 2; ++kk) {
            const int chunk = kk * 4 + kb;
            bf16x8 af[8];
            #pragma unroll
            for (int fi = 0; fi < 8; ++fi) {
                const int m = wr * 128 + fi * 16 + fr;
                af[fi] = *(const bf16x8*)&As4[m][sw_idx(m, chunk)];
            }
            #pragma unroll
            for (int fj = 0; fj < 8; ++fj) {
                const int n = wc * 128 + fj * 16 + fr;
                const bf16x8 bv = *(const bf16x8*)&Bs4[n][sw_idx(n, chunk)];
                #pragma unroll
                for (int fi = 0; fi < 8; ++fi)
                    acc[fi][fj] = __builtin_amdgcn_mfma_f32_16x16x32_bf16(
                        af[fi], bv, acc[fi][fj], 0, 0, 0);
            }
        }
        __syncthreads();
    }

    // epilogue: C/D layout n = lane&15, m = (lane>>4)*4 + v (validated)
    float* o = out + (long)l * (1024 * 1024);
    #pragma unroll
    for (int fi = 0; fi < 8; ++fi) {
        #pragma unroll
        for (int fj = 0; fj < 8; ++fj) {
            const int n = n0 + wc * 128 + fj * 16 + fr;
            #pragma unroll
            for (int v = 0; v < 4; ++v) {
                const int m = m0 + wr * 128 + fi * 16 + kb * 4 + v;
                o[(long)m * 1024 + n] = acc[fi][fj][v];
            }
        }
    }
}

extern "C" void kernel_launch(void* const* d_in, const int* in_sizes, int n_in,
                              void* d_out, int out_size, void* d_ws, size_t ws_size,
                              hipStream_t stream) {
    const float* q    = (const float*)d_in[0];  // [64,768]
    const float* keys = (const float*)d_in[1];  // [1,12,64,64]
    const float* wo   = (const float*)d_in[2];  // [64,2,1572864]
    float* out = (float*)d_out;                 // [24,1024,1024]

    int*   idx = (int*)d_ws;
    float* w   = (float*)((char*)d_ws + 32);

    routing_kernel<<<1, 768, 0, stream>>>(q, keys, idx, w);

    lowrank_mfma_kernel<<<dim3(192, 1, 1), 512, 0, stream>>>(wo, idx, w, out);
}

// Round 11
// 96.299 us; speedup vs baseline: 2.7773x; 2.7773x over previous
//
#include <hip/hip_runtime.h>
#include <hip/hip_bf16.h>

#define GROUPS 12
#define POOL   64
#define TOPK   8
#define LAYERS 24
#define RANK   64
#define HID    1024
// weight_offset: [POOL, 2, HID*RANK*LAYERS]
#define D_LR   (HID * RANK * LAYERS)      // 1572864
#define POOL_STRIDE (2L * D_LR)           // 3145728
// bf16 panel: (l,s,mat) -> 1024 cols x 8 K-chunks x 16B, chunk index XOR-swizzled
#define PAN_U4 8192                        // uint4 per panel (128 KB)
#define WS_PAN_BYTES ((size_t)LAYERS * TOPK * 2 * PAN_U4 * 16)   // 48 MB

typedef __attribute__((ext_vector_type(8))) short bf16x8;
typedef __attribute__((ext_vector_type(4))) float f32x4;

__device__ __forceinline__ unsigned bfpack2(float lo, float hi) {
    float2 t; t.x = lo; t.y = hi;
    union { __hip_bfloat162 h; unsigned u; } cv;
    cv.h = __float22bfloat162_rn(t);
    return cv.u;
}

// fallback-kernel swizzle
__device__ __forceinline__ int sw_idx(int col, int chunk) {
    return chunk ^ (col & 7) ^ ((col >> 2) & 7);
}

__device__ __forceinline__ void gll16(const void* g, void* l) {
    __builtin_amdgcn_global_load_lds(
        (const __attribute__((address_space(1))) unsigned*)g,
        (__attribute__((address_space(3))) unsigned*)l, 16, 0, 0);
}

// ---------------- Phase 1: routing (one block, 768 threads) ----------------
__global__ void routing_kernel(const float* __restrict__ q,     // [64, 768]
                               const float* __restrict__ keys,  // [12, 64, 64]
                               int* __restrict__ idx_out,       // [8]
                               float* __restrict__ w_out) {     // [8]
    __shared__ float invn[64][GROUPS];
    __shared__ float qbar[GROUPS][64];
    __shared__ float simg[GROUPS][64];
    const int t = threadIdx.x;

    {
        int b = t / GROUPS, g = t % GROUPS;
        const float* row = q + b * 768 + g * 64;
        float ss = 0.f;
        #pragma unroll 8
        for (int c = 0; c < 64; ++c) { float v = row[c]; ss = fmaf(v, v, ss); }
        invn[b][g] = 1.f / fmaxf(sqrtf(ss), 1e-8f);
    }
    __syncthreads();
    {
        int g = t >> 6, c = t & 63;
        float s = 0.f;
        for (int b = 0; b < 64; ++b) s = fmaf(q[b * 768 + g * 64 + c], invn[b][g], s);
        qbar[g][c] = s;
    }
    __syncthreads();
    {
        int g = t >> 6, p = t & 63;
        const float* krow = keys + (g * 64 + p) * 64;
        float ss = 0.f, dot = 0.f;
        #pragma unroll 8
        for (int c = 0; c < 64; ++c) {
            float v = krow[c];
            ss  = fmaf(v, v, ss);
            dot = fmaf(v, qbar[g][c], dot);
        }
        simg[g][p] = dot / fmaxf(sqrtf(ss), 1e-8f);
    }
    __syncthreads();
    if (t < 64) {
        float s = 0.f;
        for (int g = 0; g < GROUPS; ++g) s += simg[g][t];
        qbar[0][t] = s * (1.f / 768.f);
    }
    __syncthreads();
    if (t == 0) {
        float ms[POOL];
        for (int p = 0; p < POOL; ++p) ms[p] = qbar[0][p];
        float sum = 0.f;
        float vals[TOPK]; int ids[TOPK];
        for (int k = 0; k < TOPK; ++k) {
            float best = -3.4e38f; int bi = 0;
            for (int p = 0; p < POOL; ++p)
                if (ms[p] > best) { best = ms[p]; bi = p; }
            vals[k] = best; ids[k] = bi;
            ms[bi] = -3.4e38f; sum += best;
        }
        float inv = 1.f / (sum + 1e-9f);
        for (int k = 0; k < TOPK; ++k) { idx_out[k] = ids[k]; w_out[k] = vals[k] * inv; }
    }
}

// ------- Phase 1.5: gather + scale + bf16 + pre-swizzle, LDS-bounced -------
// 1536 blocks x 256 thr; block = (l, colblk, s, mat). Reads each selected fp32
// byte once (coalesced rows), packs K-chunks swizzled into LDS, then streams
// LDS->ws with lane-consecutive 16B stores (full write coalescing).
__global__ __launch_bounds__(256) void convert_kernel(
        const float* __restrict__ wo, const int* __restrict__ idx,
        const float* __restrict__ w, uint4* __restrict__ pan) {
    __shared__ uint4 lds[2048];        // 32 KB: [col(256)][swz-chunk(8)]
    const int bid = blockIdx.x;
    const int mat = bid & 1;
    const int s   = (bid >> 1) & 7;
    const int cb  = (bid >> 4) & 3;
    const int l   = bid >> 6;
    const int tid = threadIdx.x;
    const int col = cb * 256 + tid;
    const float wn = mat ? 1.0f : w[s];
    const float* src = wo + (long)idx[s] * POOL_STRIDE + (long)mat * D_LR
                     + (long)l * (RANK * HID) + col;
    float v[64];
    #pragma unroll
    for (int r = 0; r < 64; ++r) v[r] = src[(long)r * HID] * wn;
    #pragma unroll
    for (int qc = 0; qc < 8; ++qc) {
        uint4 u;
        u.x = bfpack2(v[qc*8+0], v[qc*8+1]);
        u.y = bfpack2(v[qc*8+2], v[qc*8+3]);
        u.z = bfpack2(v[qc*8+4], v[qc*8+5]);
        u.w = bfpack2(v[qc*8+6], v[qc*8+7]);
        lds[tid * 8 + (qc ^ (tid & 7))] = u;
    }
    __syncthreads();
    uint4* dst = pan + (long)((l * 8 + s) * 2 + mat) * PAN_U4 + cb * 2048;
    #pragma unroll
    for (int j = 0; j < 8; ++j) dst[j * 256 + tid] = lds[j * 256 + tid];
}

// ---- Phase 2: bf16 MFMA GEMM from panels; pure gll16 -> ds_read -> MFMA ----
// 256 blocks / 512 thr / 8 waves; 256x256 tile, BK=64; double-buffered 128 KB
// LDS, one barrier per slot, depth-1 prefetch; r6 XCD-layer-gang tile map.
__global__ __launch_bounds__(512) void lowrank_mfma2_kernel(
        const uint4* __restrict__ pan,  // ws panels
        float*       __restrict__ out)  // [24, 1024, 1024]
{
    __shared__ uint4 As4[2][256 * 8];   // [buf][col*8 + swz-chunk]
    __shared__ uint4 Bs4[2][256 * 8];

    const int tid = threadIdx.x;
    const int b   = blockIdx.x;       // 0..255
    const int xcd = b & 7;
    const int i   = b >> 3;           // 0..31

    const int tile0 = (2 * xcd + (i >> 4)) * 16 + (i & 15);
    const int nt    = (i < 16) ? 2 : 1;
    const int tile1 = (16 + xcd) * 16 + i;

    const int lane = tid & 63;
    const int wave = tid >> 6;
    const int wr = wave >> 2;      // 0..1 : 128-row band
    const int wc = wave & 3;       // 0..3 : 64-col band
    const int fr = lane & 15;
    const int kb = lane >> 4;

    f32x4 acc[8][4];
    #pragma unroll
    for (int p = 0; p < 8; ++p)
        #pragma unroll
        for (int q2 = 0; q2 < 4; ++q2) acc[p][q2] = (f32x4){0.f, 0.f, 0.f, 0.f};

    auto stage = [&](int buf, int T, int s) {
        const int l   = T >> 4;
        const int rem = T & 15;
        const int m0  = (rem >> 2) * 256;
        const int n0  = (rem & 3) * 256;
        const uint4* pa = pan + (long)((l * 8 + s) * 2 + 0) * PAN_U4 + m0 * 8;
        const uint4* pb = pan + (long)((l * 8 + s) * 2 + 1) * PAN_U4 + n0 * 8;
        // 32 KB each: 2048 uint4, 4/thread; LDS dest = wave-uniform + lane*16
        #pragma unroll
        for (int t2 = 0; t2 < 4; ++t2) {
            gll16(pa + t2 * 512 + tid, &As4[buf][t2 * 512 + wave * 64]);
            gll16(pb + t2 * 512 + tid, &Bs4[buf][t2 * 512 + wave * 64]);
        }
    };

    auto epilogue = [&](int T) {
        const int l   = T >> 4;
        const int rem = T & 15;
        const int m0  = (rem >> 2) * 256;
        const int n0  = (rem & 3) * 256;
        float* o = out + (long)l * (1024 * 1024);
        #pragma unroll
        for (int fi = 0; fi < 8; ++fi)
            #pragma unroll
            for (int fj = 0; fj < 4; ++fj) {
                const int n = n0 + wc * 64 + fj * 16 + fr;
                #pragma unroll
                for (int v = 0; v < 4; ++v) {
                    const int m = m0 + wr * 128 + fi * 16 + kb * 4 + v;
                    o[(long)m * 1024 + n] = acc[fi][fj][v];
                }
                acc[fi][fj] = (f32x4){0.f, 0.f, 0.f, 0.f};
            }
    };

    stage(0, tile0, 0);
    const int ms_total = nt * 8;
    for (int ms = 0; ms < ms_total; ++ms) {
        const int cur = ms & 1;
        __syncthreads();   // drains vmcnt: stage(cur) complete & visible
        if (ms + 1 < ms_total)
            stage(cur ^ 1, (ms + 1 < 8) ? tile0 : tile1, (ms + 1) & 7);

        #pragma unroll
        for (int kk = 0; kk < 2; ++kk) {
            const int chunk = kk * 4 + kb;
            bf16x8 bfv[4];
            #pragma unroll
            for (int fj = 0; fj < 4; ++fj) {
                const int n = wc * 64 + fj * 16 + fr;
                bfv[fj] = *(const bf16x8*)&Bs4[cur][n * 8 + (chunk ^ (n & 7))];
            }
            #pragma unroll
            for (int fi = 0; fi < 8; ++fi) {
                const int m = wr * 128 + fi * 16 + fr;
                const bf16x8 af = *(const bf16x8*)&As4[cur][m * 8 + (chunk ^ (m & 7))];
                #pragma unroll
                for (int fj = 0; fj < 4; ++fj)
                    acc[fi][fj] = __builtin_amdgcn_mfma_f32_16x16x32_bf16(
                        af, bfv[fj], acc[fi][fj], 0, 0, 0);
            }
        }
        if ((ms & 7) == 7) epilogue(ms < 8 ? tile0 : tile1);
    }
}

// ---------------- Fallback (round-6 fused kernel) if ws too small ----------------
__global__ __launch_bounds__(512, 2) void lowrank_mfma_kernel(
        const float* __restrict__ wo, const int* __restrict__ idx,
        const float* __restrict__ w, float* __restrict__ out)
{
    __shared__ uint4 As4[256][8];
    __shared__ uint4 Bs4[256][8];
    __shared__ int   s_idx[TOPK];
    __shared__ float s_w[TOPK];

    const int tid = threadIdx.x;
    const int b   = blockIdx.x;
    const int xcd = b & 7;
    const int i   = b >> 3;
    const int tile0 = (2 * xcd + (i >> 4)) * 16 + (i & 15);
    const int nt    = (i < 16) ? 2 : 1;
    const int tile1 = (16 + xcd) * 16 + i;

    if (tid < TOPK) { s_idx[tid] = idx[tid]; s_w[tid] = w[tid]; }
    __syncthreads();

    const int lane = tid & 63;
    const int wave = tid >> 6;
    const int wr = wave >> 2, wc = wave & 3;
    const int fr = lane & 15, kb = lane >> 4;
    const int c4 = lane, rg = wave;

    f32x4 acc[8][4];
    #pragma unroll
    for (int p = 0; p < 8; ++p)
        #pragma unroll
        for (int q2 = 0; q2 < 4; ++q2) acc[p][q2] = (f32x4){0.f, 0.f, 0.f, 0.f};

    f32x4 araw[8], braw[8];
    auto load_raw = [&](int T, int s) {
        const int l = T >> 4, rem = T & 15;
        const int m0 = (rem >> 2) * 256, n0 = (rem & 3) * 256;
        const long base = (long)s_idx[s] * POOL_STRIDE + (long)l * (RANK * HID);
        const float* pa = wo + base + (long)(rg * 8) * HID + (m0 + c4 * 4);
        const float* pb = wo + base + D_LR + (long)(rg * 8) * HID + (n0 + c4 * 4);
        #pragma unroll
        for (int j = 0; j < 8; ++j) araw[j] = *(const f32x4*)(pa + (long)j * HID);
        #pragma unroll
        for (int j = 0; j < 8; ++j) braw[j] = *(const f32x4*)(pb + (long)j * HID);
    };

    load_raw(tile0, 0);
    for (int ti = 0; ti < nt; ++ti) {
        const int T = (ti == 0) ? tile0 : tile1;
        const int l = T >> 4, rem = T & 15;
        const int m0 = (rem >> 2) * 256, n0 = (rem & 3) * 256;
        for (int s = 0; s < 8; ++s) {
            const float wn = s_w[s];
            #pragma unroll
            for (int cc = 0; cc < 4; ++cc) {
                const int col = c4 * 4 + cc;
                uint4 ua, ub;
                ua.x = bfpack2(wn * araw[0][cc], wn * araw[1][cc]);
                ua.y = bfpack2(wn * araw[2][cc], wn * araw[3][cc]);
                ua.z = bfpack2(wn * araw[4][cc], wn * araw[5][cc]);
                ua.w = bfpack2(wn * araw[6][cc], wn * araw[7][cc]);
                ub.x = bfpack2(braw[0][cc], braw[1][cc]);
                ub.y = bfpack2(braw[2][cc], braw[3][cc]);
                ub.z = bfpack2(braw[4][cc], braw[5][cc]);
                ub.w = bfpack2(braw[6][cc], braw[7][cc]);
                const int cp = sw_idx(col, rg);
                As4[col][cp] = ua;
                Bs4[col][cp] = ub;
            }
            __syncthreads();
            if (s < 7)            load_raw(T, s + 1);
            else if (ti + 1 < nt) load_raw(tile1, 0);
            #pragma unroll
            for (int kk = 0; kk < 2; ++kk) {
                const int chunk = kk * 4 + kb;
                bf16x8 bfv[4];
                #pragma unroll
                for (int fj = 0; fj < 4; ++fj) {
                    const int n = wc * 64 + fj * 16 + fr;
                    bfv[fj] = *(const bf16x8*)&Bs4[n][sw_idx(n, chunk)];
                }
                #pragma unroll
                for (int fi = 0; fi < 8; ++fi) {
                    const int m = wr * 128 + fi * 16 + fr;
                    const bf16x8 af = *(const bf16x8*)&As4[m][sw_idx(m, chunk)];
                    #pragma unroll
                    for (int fj = 0; fj < 4; ++fj)
                        acc[fi][fj] = __builtin_amdgcn_mfma_f32_16x16x32_bf16(
                            af, bfv[fj], acc[fi][fj], 0, 0, 0);
                }
            }
            __syncthreads();
        }
        float* o = out + (long)l * (1024 * 1024);
        #pragma unroll
        for (int fi = 0; fi < 8; ++fi)
            #pragma unroll
            for (int fj = 0; fj < 4; ++fj) {
                const int n = n0 + wc * 64 + fj * 16 + fr;
                #pragma unroll
                for (int v = 0; v < 4; ++v) {
                    const int m = m0 + wr * 128 + fi * 16 + kb * 4 + v;
                    o[(long)m * 1024 + n] = acc[fi][fj][v];
                }
                acc[fi][fj] = (f32x4){0.f, 0.f, 0.f, 0.f};
            }
    }
}

extern "C" void kernel_launch(void* const* d_in, const int* in_sizes, int n_in,
                              void* d_out, int out_size, void* d_ws, size_t ws_size,
                              hipStream_t stream) {
    const float* q    = (const float*)d_in[0];  // [64,768]
    const float* keys = (const float*)d_in[1];  // [1,12,64,64]
    const float* wo   = (const float*)d_in[2];  // [64,2,1572864]
    float* out = (float*)d_out;                 // [24,1024,1024]

    int*   idx = (int*)d_ws;
    float* w   = (float*)((char*)d_ws + 32);
    uint4* pan = (uint4*)((char*)d_ws + 1024);

    routing_kernel<<<1, 768, 0, stream>>>(q, keys, idx, w);

    if (ws_size >= 1024 + WS_PAN_BYTES) {
        convert_kernel<<<dim3(1536, 1, 1), 256, 0, stream>>>(wo, idx, w, pan);
        lowrank_mfma2_kernel<<<dim3(256, 1, 1), 512, 0, stream>>>(pan, out);
    } else {
        lowrank_mfma_kernel<<<dim3(256, 1, 1), 512, 0, stream>>>(wo, idx, w, out);
    }
}

// Round 12
// 80.260 us; speedup vs baseline: 3.3323x; 1.1998x over previous
//
#include <hip/hip_runtime.h>
#include <hip/hip_bf16.h>

#define GROUPS 12
#define POOL   64
#define TOPK   8
#define LAYERS 24
#define RANK   64
#define HID    1024
// weight_offset: [POOL, 2, HID*RANK*LAYERS]
#define D_LR   (HID * RANK * LAYERS)      // 1572864
#define POOL_STRIDE (2L * D_LR)           // 3145728

typedef __attribute__((ext_vector_type(8))) short bf16x8;
typedef __attribute__((ext_vector_type(4))) float f32x4;

__device__ __forceinline__ unsigned bfpack2(float lo, float hi) {
    float2 t; t.x = lo; t.y = hi;
    union { __hip_bfloat162 h; unsigned u; } cv;
    cv.h = __float22bfloat162_rn(t);
    return cv.u;
}

// XOR swizzle on the K-chunk index; conflict-free for both the b128 write
// pattern (col=4*lane+cc, chunk=rg) and read (col=base+fr, chunk=kk*4+kb)
__device__ __forceinline__ int sw_idx(int col, int chunk) {
    return chunk ^ (col & 7) ^ ((col >> 2) & 7);
}

// ---------------- Phase 1: routing (one block, 768 threads) ----------------
__global__ void routing_kernel(const float* __restrict__ q,     // [64, 768]
                               const float* __restrict__ keys,  // [12, 64, 64]
                               int* __restrict__ idx_out,       // [8]
                               float* __restrict__ w_out) {     // [8]
    __shared__ float invn[64][GROUPS];
    __shared__ float qbar[GROUPS][64];
    __shared__ float simg[GROUPS][64];
    const int t = threadIdx.x;

    {
        int b = t / GROUPS, g = t % GROUPS;
        const float* row = q + b * 768 + g * 64;
        float ss = 0.f;
        #pragma unroll 8
        for (int c = 0; c < 64; ++c) { float v = row[c]; ss = fmaf(v, v, ss); }
        invn[b][g] = 1.f / fmaxf(sqrtf(ss), 1e-8f);
    }
    __syncthreads();
    {
        int g = t >> 6, c = t & 63;
        float s = 0.f;
        for (int b = 0; b < 64; ++b) s = fmaf(q[b * 768 + g * 64 + c], invn[b][g], s);
        qbar[g][c] = s;
    }
    __syncthreads();
    {
        int g = t >> 6, p = t & 63;
        const float* krow = keys + (g * 64 + p) * 64;
        float ss = 0.f, dot = 0.f;
        #pragma unroll 8
        for (int c = 0; c < 64; ++c) {
            float v = krow[c];
            ss  = fmaf(v, v, ss);
            dot = fmaf(v, qbar[g][c], dot);
        }
        simg[g][p] = dot / fmaxf(sqrtf(ss), 1e-8f);
    }
    __syncthreads();
    if (t < 64) {
        float s = 0.f;
        for (int g = 0; g < GROUPS; ++g) s += simg[g][t];
        qbar[0][t] = s * (1.f / 768.f);
    }
    __syncthreads();
    if (t == 0) {
        float ms[POOL];
        for (int p = 0; p < POOL; ++p) ms[p] = qbar[0][p];
        float sum = 0.f;
        float vals[TOPK]; int ids[TOPK];
        for (int k = 0; k < TOPK; ++k) {
            float best = -3.4e38f; int bi = 0;
            for (int p = 0; p < POOL; ++p)
                if (ms[p] > best) { best = ms[p]; bi = p; }
            vals[k] = best; ids[k] = bi;
            ms[bi] = -3.4e38f; sum += best;
        }
        float inv = 1.f / (sum + 1e-9f);
        for (int k = 0; k < TOPK; ++k) { idx_out[k] = ids[k]; w_out[k] = vals[k] * inv; }
    }
}

// ---- Phase 2: bf16 MFMA GEMM, 256x256 tiles, 512 thr / 8 waves (round-6
// empirical optimum: sits at the issued-bytes/achievable-BW roofline). ----
__global__ __launch_bounds__(512, 2) void lowrank_mfma_kernel(
        const float* __restrict__ wo,   // [64, 2, D_LR]
        const int*   __restrict__ idx,  // [8]
        const float* __restrict__ w,    // [8]
        float*       __restrict__ out)  // [24, 1024, 1024]
{
    __shared__ uint4 As4[256][8];   // [col][K-chunk of 8 bf16], swizzled
    __shared__ uint4 Bs4[256][8];
    __shared__ int   s_idx[TOPK];
    __shared__ float s_w[TOPK];

    const int tid = threadIdx.x;
    const int b   = blockIdx.x;       // 0..255
    const int xcd = b & 7;            // assumed round-robin block->XCD
    const int i   = b >> 3;           // 0..31 within XCD

    // tile ids: T = l*16 + (m-idx*4 + n-idx)
    const int tile0 = (2 * xcd + (i >> 4)) * 16 + (i & 15);
    const int nt    = (i < 16) ? 2 : 1;
    const int tile1 = (16 + xcd) * 16 + i;   // valid only when nt==2

    if (tid < TOPK) { s_idx[tid] = idx[tid]; s_w[tid] = w[tid]; }
    __syncthreads();

    const int lane = tid & 63;
    const int wave = tid >> 6;
    const int wr = wave >> 2;      // 0..1 : 128-row band
    const int wc = wave & 3;       // 0..3 : 64-col band
    const int fr = lane & 15;
    const int kb = lane >> 4;

    const int c4 = lane;           // column quad 0..63 (4 cols each)
    const int rg = wave;           // K-row octet 0..7 = chunk

    f32x4 acc[8][4];
    #pragma unroll
    for (int p = 0; p < 8; ++p)
        #pragma unroll
        for (int q2 = 0; q2 < 4; ++q2) acc[p][q2] = (f32x4){0.f, 0.f, 0.f, 0.f};

    f32x4 araw[8], braw[8];

    auto load_raw = [&](int T, int s) {
        const int l   = T >> 4;
        const int rem = T & 15;
        const int m0  = (rem >> 2) * 256;
        const int n0  = (rem & 3) * 256;
        const long base = (long)s_idx[s] * POOL_STRIDE + (long)l * (RANK * HID);
        const float* pa = wo + base + (long)(rg * 8) * HID + (m0 + c4 * 4);
        const float* pb = wo + base + D_LR + (long)(rg * 8) * HID + (n0 + c4 * 4);
        #pragma unroll
        for (int j = 0; j < 8; ++j) araw[j] = *(const f32x4*)(pa + (long)j * HID);
        #pragma unroll
        for (int j = 0; j < 8; ++j) braw[j] = *(const f32x4*)(pb + (long)j * HID);
    };

    load_raw(tile0, 0);

    for (int ti = 0; ti < nt; ++ti) {
        const int T   = (ti == 0) ? tile0 : tile1;
        const int l   = T >> 4;
        const int rem = T & 15;
        const int m0  = (rem >> 2) * 256;
        const int n0  = (rem & 3) * 256;

        for (int s = 0; s < 8; ++s) {
            // pack previously-loaded slot s: 8 K-rows x 4 cols -> K-contig chunks
            const float wn = s_w[s];
            #pragma unroll
            for (int cc = 0; cc < 4; ++cc) {
                const int col = c4 * 4 + cc;
                uint4 ua, ub;
                ua.x = bfpack2(wn * araw[0][cc], wn * araw[1][cc]);
                ua.y = bfpack2(wn * araw[2][cc], wn * araw[3][cc]);
                ua.z = bfpack2(wn * araw[4][cc], wn * araw[5][cc]);
                ua.w = bfpack2(wn * araw[6][cc], wn * araw[7][cc]);
                ub.x = bfpack2(braw[0][cc], braw[1][cc]);
                ub.y = bfpack2(braw[2][cc], braw[3][cc]);
                ub.z = bfpack2(braw[4][cc], braw[5][cc]);
                ub.w = bfpack2(braw[6][cc], braw[7][cc]);
                const int cp = sw_idx(col, rg);
                As4[col][cp] = ua;
                Bs4[col][cp] = ub;
            }
            __syncthreads();

            // prefetch next slot (or next tile's slot 0) under the MFMA cluster
            if (s < 7)            load_raw(T, s + 1);
            else if (ti + 1 < nt) load_raw(tile1, 0);

            #pragma unroll
            for (int kk = 0; kk < 2; ++kk) {
                const int chunk = kk * 4 + kb;
                bf16x8 bfv[4];
                #pragma unroll
                for (int fj = 0; fj < 4; ++fj) {
                    const int n = wc * 64 + fj * 16 + fr;
                    bfv[fj] = *(const bf16x8*)&Bs4[n][sw_idx(n, chunk)];
                }
                #pragma unroll
                for (int fi = 0; fi < 8; ++fi) {
                    const int m = wr * 128 + fi * 16 + fr;
                    const bf16x8 af = *(const bf16x8*)&As4[m][sw_idx(m, chunk)];
                    #pragma unroll
                    for (int fj = 0; fj < 4; ++fj)
                        acc[fi][fj] = __builtin_amdgcn_mfma_f32_16x16x32_bf16(
                            af, bfv[fj], acc[fi][fj], 0, 0, 0);
                }
            }
            __syncthreads();
        }

        // epilogue: C/D layout n = lane&15, m = (lane>>4)*4 + v (validated)
        float* o = out + (long)l * (1024 * 1024);
        #pragma unroll
        for (int fi = 0; fi < 8; ++fi) {
            #pragma unroll
            for (int fj = 0; fj < 4; ++fj) {
                const int n = n0 + wc * 64 + fj * 16 + fr;
                #pragma unroll
                for (int v = 0; v < 4; ++v) {
                    const int m = m0 + wr * 128 + fi * 16 + kb * 4 + v;
                    o[(long)m * 1024 + n] = acc[fi][fj][v];
                }
                acc[fi][fj] = (f32x4){0.f, 0.f, 0.f, 0.f};
            }
        }
    }
}

extern "C" void kernel_launch(void* const* d_in, const int* in_sizes, int n_in,
                              void* d_out, int out_size, void* d_ws, size_t ws_size,
                              hipStream_t stream) {
    const float* q    = (const float*)d_in[0];  // [64,768]
    const float* keys = (const float*)d_in[1];  // [1,12,64,64]
    const float* wo   = (const float*)d_in[2];  // [64,2,1572864]
    float* out = (float*)d_out;                 // [24,1024,1024]

    int*   idx = (int*)d_ws;
    float* w   = (float*)((char*)d_ws + 32);

    routing_kernel<<<1, 768, 0, stream>>>(q, keys, idx, w);

    lowrank_mfma_kernel<<<dim3(256, 1, 1), 512, 0, stream>>>(wo, idx, w, out);
}